// Round 15
// baseline (575.068 us; speedup 1.0000x reference)
//
#include <hip/hip_runtime.h>

#define NT 2048
#define Dm 768
#define Fm 3072
#define Bm 16
#define Sm 128
#define Hm 12
#define DHm 64

#define BM 64
#define BM2 128
#define BN 128
#define BK 32

typedef __attribute__((ext_vector_type(8))) short bf16x8;
typedef __attribute__((ext_vector_type(4))) float f32x4;

__device__ __forceinline__ unsigned short f2bf(float f){
  unsigned u = __float_as_uint(f);
  unsigned r = (u + 0x7fffu + ((u>>16)&1u)) >> 16;   // round-nearest-even
  return (unsigned short)r;
}
__device__ __forceinline__ float bf2f(unsigned short h){ return __uint_as_float(((unsigned)h)<<16); }
__device__ __forceinline__ unsigned fsplit2(float x){
  unsigned short h = f2bf(x);
  unsigned short l = f2bf(x - bf2f(h));
  return (unsigned)h | ((unsigned)l << 16);
}
// fast hi/lo split of TWO floats via hardware packed cvt (RNE, bit-identical to f2bf):
__device__ __forceinline__ void bsplit2(float a, float b, unsigned &hi2, unsigned &lo2){
  asm("v_cvt_pk_bf16_f32 %0, %1, %2" : "=v"(hi2) : "v"(a), "v"(b));
  float fa = __uint_as_float(hi2 << 16);
  float fb = __uint_as_float(hi2 & 0xffff0000u);
  asm("v_cvt_pk_bf16_f32 %0, %1, %2" : "=v"(lo2) : "v"(a - fa), "v"(b - fb));
}
__device__ __forceinline__ float gelu_f(float x){
  return 0.5f*x*(1.0f + erff(x*0.70710678118654752f));
}

// ========== barrier-free reg-direct bf16 tile loop, BM2=128, 1-deep prefetch ==========
__device__ __forceinline__ void mm_tile2(
    const short* __restrict__ Abf, int lda,
    const int* __restrict__ gidx, int m0, int mbound,
    const float* __restrict__ W0, int N, int K, int n0,
    f32x4 acc[4][4])
{
  int lane = threadIdx.x & 63, wv = threadIdx.x >> 6;
  int wm = wv & 1, wn = wv >> 1;
  int oct = lane >> 4, l16 = lane & 15;
  const short* aptr[4];
  #pragma unroll
  for(int fi=0; fi<4; fi++){
    int lr = wm*64 + fi*16 + l16;
    int grow = (lr < mbound) ? (gidx ? gidx[m0 + lr] : (m0 + lr)) : -1;
    aptr[fi] = (grow >= 0) ? (Abf + (size_t)grow*lda + oct*8) : nullptr;
  }
  const float* bptr[4];
  #pragma unroll
  for(int fj=0; fj<4; fj++)
    bptr[fj] = W0 + (size_t)(oct*8)*N + (n0 + wn*64 + fj*16 + l16);

  const bf16x8 zz = {0,0,0,0,0,0,0,0};
  bf16x8 av[4]; float bw[4][8];
  #pragma unroll
  for(int fi=0; fi<4; fi++) av[fi] = aptr[fi] ? *(const bf16x8*)(aptr[fi]) : zz;
  #pragma unroll
  for(int fj=0; fj<4; fj++)
    #pragma unroll
    for(int i=0;i<8;i++) bw[fj][i] = bptr[fj][(size_t)i*N];

  for(int k0=0; k0<K; k0+=BK){
    bf16x8 af[4];
    #pragma unroll
    for(int fi=0; fi<4; fi++) af[fi] = av[fi];
    bf16x8 bfr[4];
    #pragma unroll
    for(int fj=0; fj<4; fj++){
      unsigned o0,o1,o2,o3;
      asm("v_cvt_pk_bf16_f32 %0, %1, %2" : "=v"(o0) : "v"(bw[fj][0]), "v"(bw[fj][1]));
      asm("v_cvt_pk_bf16_f32 %0, %1, %2" : "=v"(o1) : "v"(bw[fj][2]), "v"(bw[fj][3]));
      asm("v_cvt_pk_bf16_f32 %0, %1, %2" : "=v"(o2) : "v"(bw[fj][4]), "v"(bw[fj][5]));
      asm("v_cvt_pk_bf16_f32 %0, %1, %2" : "=v"(o3) : "v"(bw[fj][6]), "v"(bw[fj][7]));
      union{ bf16x8 v; unsigned u[4]; } r;
      r.u[0]=o0; r.u[1]=o1; r.u[2]=o2; r.u[3]=o3;
      bfr[fj] = r.v;
    }
    if(k0+BK < K){
      int kn = k0 + BK;
      #pragma unroll
      for(int fi=0; fi<4; fi++) av[fi] = aptr[fi] ? *(const bf16x8*)(aptr[fi] + kn) : zz;
      #pragma unroll
      for(int fj=0; fj<4; fj++)
        #pragma unroll
        for(int i=0;i<8;i++) bw[fj][i] = bptr[fj][(size_t)(kn + i)*N];
    }
    __builtin_amdgcn_s_setprio(1);
    #pragma unroll
    for(int fi=0; fi<4; fi++)
      #pragma unroll
      for(int fj=0; fj<4; fj++)
        acc[fi][fj] = __builtin_amdgcn_mfma_f32_16x16x32_bf16(af[fi], bfr[fj], acc[fi][fj], 0, 0, 0);
    __builtin_amdgcn_s_setprio(0);
  }
}

// ===== barrier-free split-bf16 tile loop: A pre-split hi/lo, W fast-split via cvt_pk =====
__device__ __forceinline__ void mm_tile3b(
    const short* __restrict__ Ahi, const short* __restrict__ Alo, int lda, int m0, int acol,
    const float* __restrict__ W0, int N, int K, int n0,
    f32x4 acc[2][4])
{
  int lane = threadIdx.x & 63, wv = threadIdx.x >> 6;
  int wm = wv & 1, wn = wv >> 1;
  int oct = lane >> 4, l16 = lane & 15;
  size_t aoffs[2];
  #pragma unroll
  for(int fi=0; fi<2; fi++){
    int lr = wm*32 + fi*16 + l16;
    aoffs[fi] = (size_t)(m0 + lr)*lda + acol + oct*8;
  }
  const float* bptr[4];
  #pragma unroll
  for(int fj=0; fj<4; fj++)
    bptr[fj] = W0 + (size_t)(oct*8)*N + (n0 + wn*64 + fj*16 + l16);

  bf16x8 avH[2], avL[2]; float bw[4][8];
  #pragma unroll
  for(int fi=0; fi<2; fi++){
    avH[fi] = *(const bf16x8*)(Ahi + aoffs[fi]);
    avL[fi] = *(const bf16x8*)(Alo + aoffs[fi]);
  }
  #pragma unroll
  for(int fj=0; fj<4; fj++)
    #pragma unroll
    for(int i=0;i<8;i++) bw[fj][i] = bptr[fj][(size_t)i*N];

  for(int k0=0; k0<K; k0+=BK){
    bf16x8 ah[2], al[2];
    #pragma unroll
    for(int fi=0; fi<2; fi++){ ah[fi]=avH[fi]; al[fi]=avL[fi]; }
    bf16x8 bh[4], bl[4];
    #pragma unroll
    for(int fj=0; fj<4; fj++){
      unsigned h0,l0,h1,l1,h2,l2,h3,l3;
      bsplit2(bw[fj][0], bw[fj][1], h0, l0);
      bsplit2(bw[fj][2], bw[fj][3], h1, l1);
      bsplit2(bw[fj][4], bw[fj][5], h2, l2);
      bsplit2(bw[fj][6], bw[fj][7], h3, l3);
      union{ bf16x8 v; unsigned u[4]; } rh, rl;
      rh.u[0]=h0; rh.u[1]=h1; rh.u[2]=h2; rh.u[3]=h3;
      rl.u[0]=l0; rl.u[1]=l1; rl.u[2]=l2; rl.u[3]=l3;
      bh[fj] = rh.v; bl[fj] = rl.v;
    }
    if(k0+BK < K){
      int kn = k0 + BK;
      #pragma unroll
      for(int fi=0; fi<2; fi++){
        avH[fi] = *(const bf16x8*)(Ahi + aoffs[fi] + kn);
        avL[fi] = *(const bf16x8*)(Alo + aoffs[fi] + kn);
      }
      #pragma unroll
      for(int fj=0; fj<4; fj++)
        #pragma unroll
        for(int i=0;i<8;i++) bw[fj][i] = bptr[fj][(size_t)(kn + i)*N];
    }
    __builtin_amdgcn_s_setprio(1);
    #pragma unroll
    for(int fi=0; fi<2; fi++)
      #pragma unroll
      for(int fj=0; fj<4; fj++){
        acc[fi][fj] = __builtin_amdgcn_mfma_f32_16x16x32_bf16(ah[fi], bh[fj], acc[fi][fj], 0, 0, 0);
        acc[fi][fj] = __builtin_amdgcn_mfma_f32_16x16x32_bf16(ah[fi], bl[fj], acc[fi][fj], 0, 0, 0);
        acc[fi][fj] = __builtin_amdgcn_mfma_f32_16x16x32_bf16(al[fi], bh[fj], acc[fi][fj], 0, 0, 0);
      }
    __builtin_amdgcn_s_setprio(0);
  }
}

// ================= x -> hi/lo bf16 pre-split =================
__global__ __launch_bounds__(256) void k_split_x(const float* __restrict__ in,
    short* __restrict__ hi, short* __restrict__ lo, int n4){
  int i = blockIdx.x*256 + threadIdx.x;
  if(i < n4){
    float4 v = ((const float4*)in)[i];
    unsigned h01,l01,h23,l23;
    bsplit2(v.x, v.y, h01, l01);
    bsplit2(v.z, v.w, h23, l23);
    short4 h, l;
    h.x=(short)(h01&0xffff); h.y=(short)(h01>>16); h.z=(short)(h23&0xffff); h.w=(short)(h23>>16);
    l.x=(short)(l01&0xffff); l.y=(short)(l01>>16); l.z=(short)(l23&0xffff); l.w=(short)(l23>>16);
    ((short4*)hi)[i] = h;
    ((short4*)lo)[i] = l;
  }
}

// ================= fused QKV (common + unique), split precision, f32 out =================
struct PtrArr6 { const float* w[6]; const float* b[6]; };

__global__ __launch_bounds__(256) void mm3_qkv(const short* __restrict__ x_hi,
    const short* __restrict__ x_lo, PtrArr6 pa,
    const int* __restrict__ routeb, float* __restrict__ qkvout)
{
  int n0 = blockIdx.x*BN, m0 = blockIdx.y*BM, z = blockIdx.z;
  int bidx = m0 >> 7;
  const float* W = pa.w[z]; const float* bias = pa.b[z];
  if(z >= 3){ int e = routeb[bidx]; W += (size_t)e*Dm*Dm; bias += (size_t)e*Dm; }
  f32x4 acc[2][4] = {};
  mm_tile3b(x_hi, x_lo, Dm, m0, 0, W, Dm, Dm, n0, acc);
  float* outp = qkvout + (size_t)z*NT*Dm;
  int lane = threadIdx.x&63, wv = threadIdx.x>>6, wm = wv&1, wn = wv>>1;
  #pragma unroll
  for(int fi=0; fi<2; fi++)
    #pragma unroll
    for(int fj=0; fj<4; fj++)
      #pragma unroll
      for(int r=0; r<4; r++){
        int row = m0 + wm*32 + fi*16 + ((lane>>4)<<2) + r;
        int col = n0 + wn*64 + fj*16 + (lane&15);
        outp[(size_t)row*Dm + col] = acc[fi][fj][r] + bias[col];
      }
}

// ====== output projection, split-K=4 via z: kc/2 selects {common,unique}, kc&1 selects k-half ======
__global__ __launch_bounds__(256) void mm3_outproj(const short* __restrict__ ctx_hi,
    const short* __restrict__ ctx_lo,
    const float* __restrict__ ca_wo, const float* __restrict__ ua_wo,
    const float* __restrict__ ca_bo, const float* __restrict__ ua_bo,
    const int* __restrict__ routeb, const float* __restrict__ pmaxb,
    float* __restrict__ att4)
{
  const int KC = Dm/2;   // 384
  int n0 = blockIdx.x*BN, m0 = blockIdx.y*BM, kc = blockIdx.z;
  int bidx = m0 >> 7;
  int e = routeb[bidx];
  int uq = kc >> 1, kh = kc & 1;
  const float* Wb = uq ? (ua_wo + (size_t)e*Dm*Dm) : ca_wo;
  const float* W  = Wb + (size_t)kh*KC*Dm;
  int acol = uq*Dm + kh*KC;
  f32x4 acc[2][4] = {};
  mm_tile3b(ctx_hi, ctx_lo, 1536, m0, acol, W, Dm, KC, n0, acc);
  float* outp = att4 + (size_t)kc*NT*Dm;
  int lane = threadIdx.x&63, wv = threadIdx.x>>6, wm = wv&1, wn = wv>>1;
  #pragma unroll
  for(int fi=0; fi<2; fi++)
    #pragma unroll
    for(int fj=0; fj<4; fj++)
      #pragma unroll
      for(int r=0; r<4; r++){
        int row = m0 + wm*32 + fi*16 + ((lane>>4)<<2) + r;
        int col = n0 + wn*64 + fj*16 + (lane&15);
        float bv = 0.f;
        if(kh == 0) bv = uq ? pmaxb[bidx]*ua_bo[(size_t)e*Dm + col] : ca_bo[col];
        outp[(size_t)row*Dm + col] = acc[fi][fj][r] + bv;
      }
}

// ================= att = sum of 4 partials; also emit bf16 =================
__global__ __launch_bounds__(256) void k_att_sum(const float* __restrict__ att4,
    float* __restrict__ att, short* __restrict__ attbf, int n4){
  int i = blockIdx.x*256 + threadIdx.x;
  if(i < n4){
    const size_t P4 = (size_t)NT*Dm/4;
    float4 a = ((const float4*)att4)[i];
    float4 b = ((const float4*)att4)[P4 + i];
    float4 c = ((const float4*)att4)[2*P4 + i];
    float4 d = ((const float4*)att4)[3*P4 + i];
    float4 v;
    v.x=a.x+b.x+c.x+d.x; v.y=a.y+b.y+c.y+d.y;
    v.z=a.z+b.z+c.z+d.z; v.w=a.w+b.w+c.w+d.w;
    ((float4*)att)[i] = v;
    short4 o;
    o.x=(short)f2bf(v.x); o.y=(short)f2bf(v.y); o.z=(short)f2bf(v.z); o.w=(short)f2bf(v.w);
    ((short4*)attbf)[i] = o;
  }
}

// ===== F-stage split-K=2 (z=kc): bf16 pre-activation partials (bias in kc=0, no gelu) =====
__global__ __launch_bounds__(256) void mm_fstage(const short* __restrict__ attbf,
    const float* __restrict__ cf_w1, const float* __restrict__ cf_b1,
    const float* __restrict__ uf_w1, const float* __restrict__ uf_b1,
    const int* __restrict__ idxl, const int* __restrict__ gbase, const int* __restrict__ gcnt,
    const int* __restrict__ tlist, const int* __restrict__ ntl,
    short* __restrict__ hp, short* __restrict__ hgp)
{
  const int KC = Dm/2;   // 384
  int n0 = blockIdx.x*BN, y = blockIdx.y, kc = blockIdx.z;
  int lane = threadIdx.x&63, wv = threadIdx.x>>6, wm = wv&1, wn = wv>>1;
  f32x4 acc[4][4] = {};
  if(y < 16){
    int m0 = y*BM2;
    mm_tile2(attbf + kc*KC, Dm, nullptr, m0, BM2, cf_w1 + (size_t)kc*KC*Fm, Fm, KC, n0, acc);
    short* outp = hp + (size_t)kc*NT*Fm;
    #pragma unroll
    for(int fi=0; fi<4; fi++)
      #pragma unroll
      for(int fj=0; fj<4; fj++)
        #pragma unroll
        for(int r=0; r<4; r++){
          int row = m0 + wm*64 + fi*16 + ((lane>>4)<<2) + r;
          int col = n0 + wn*64 + fj*16 + (lane&15);
          outp[(size_t)row*Fm + col] = (short)f2bf(acc[fi][fj][r] + (kc==0 ? cf_b1[col] : 0.f));
        }
  } else {
    int i = y - 16;
    if(i >= ntl[0]) return;
    int v = tlist[i], g = v>>8, t = v&255;
    int cnt = gcnt[g], r0 = t*BM2, pos0 = gbase[g] + r0;
    mm_tile2(attbf + kc*KC, Dm, idxl, pos0, cnt - r0,
             uf_w1 + (size_t)g*Dm*Fm + (size_t)kc*KC*Fm, Fm, KC, n0, acc);
    const float* bias = uf_b1 + (size_t)g*Fm;
    short* outp = hgp + (size_t)kc*NT*Fm;
    #pragma unroll
    for(int fi=0; fi<4; fi++)
      #pragma unroll
      for(int fj=0; fj<4; fj++)
        #pragma unroll
        for(int r=0; r<4; r++){
          int lr = wm*64 + fi*16 + ((lane>>4)<<2) + r;
          if(r0 + lr >= cnt) continue;
          int col = n0 + wn*64 + fj*16 + (lane&15);
          outp[(size_t)(pos0+lr)*Fm + col] = (short)f2bf(acc[fi][fj][r] + (kc==0 ? bias[col] : 0.f));
        }
  }
}

// ===== combine F-stage partials: out = bf16(gelu(c0+c1)), in place over c0 =====
__global__ __launch_bounds__(256) void k_hcombine(const short* __restrict__ c1,
    short* __restrict__ c0out, int n4){
  int i = blockIdx.x*256 + threadIdx.x;
  if(i < n4){
    short4 a = ((const short4*)c0out)[i];
    short4 b = ((const short4*)c1)[i];
    short4 o;
    o.x = (short)f2bf(gelu_f(bf2f((unsigned short)a.x) + bf2f((unsigned short)b.x)));
    o.y = (short)f2bf(gelu_f(bf2f((unsigned short)a.y) + bf2f((unsigned short)b.y)));
    o.z = (short)f2bf(gelu_f(bf2f((unsigned short)a.z) + bf2f((unsigned short)b.z)));
    o.w = (short)f2bf(gelu_f(bf2f((unsigned short)a.w) + bf2f((unsigned short)b.w)));
    ((short4*)c0out)[i] = o;
  }
}

// ===== D-stage: panel-major grid (x = bx%6, kc = bx/6), same-panel blocks co-XCD =====
__global__ __launch_bounds__(256) void mm_dstage(const short* __restrict__ h,
    const short* __restrict__ hg,
    const float* __restrict__ cf_w2, const float* __restrict__ cf_b2,
    const float* __restrict__ uf_w2, const float* __restrict__ uf_b2,
    const int* __restrict__ idxl, const int* __restrict__ gbase, const int* __restrict__ gcnt,
    const int* __restrict__ tlist, const int* __restrict__ ntl,
    const float* __restrict__ tokp, short* __restrict__ ycf4, short* __restrict__ yuo4)
{
  const int KC = Fm/4;   // 768
  int bx = blockIdx.x;
  int n0 = (bx % 6)*BN, kc = bx / 6;
  int y = blockIdx.y;
  int lane = threadIdx.x&63, wv = threadIdx.x>>6, wm = wv&1, wn = wv>>1;
  f32x4 acc[4][4] = {};
  if(y < 16){
    int m0 = y*BM2;
    mm_tile2(h + kc*KC, Fm, nullptr, m0, BM2, cf_w2 + (size_t)kc*KC*Dm, Dm, KC, n0, acc);
    short* outp = ycf4 + (size_t)kc*NT*Dm;
    #pragma unroll
    for(int fi=0; fi<4; fi++)
      #pragma unroll
      for(int fj=0; fj<4; fj++)
        #pragma unroll
        for(int r=0; r<4; r++){
          int row = m0 + wm*64 + fi*16 + ((lane>>4)<<2) + r;
          int col = n0 + wn*64 + fj*16 + (lane&15);
          outp[(size_t)row*Dm + col] = (short)f2bf(acc[fi][fj][r] + (kc==0 ? cf_b2[col] : 0.f));
        }
  } else {
    int i = y - 16;
    if(i >= ntl[0]) return;
    int v = tlist[i], g = v>>8, t = v&255;
    int cnt = gcnt[g], r0 = t*BM2, pos0 = gbase[g] + r0;
    mm_tile2(hg + kc*KC, Fm, nullptr, pos0, cnt - r0,
             uf_w2 + (size_t)g*Fm*Dm + (size_t)kc*KC*Dm, Dm, KC, n0, acc);
    const float* bias = uf_b2 + (size_t)g*Dm;
    short* outp = yuo4 + (size_t)kc*NT*Dm;
    #pragma unroll
    for(int fi=0; fi<4; fi++)
      #pragma unroll
      for(int fj=0; fj<4; fj++)
        #pragma unroll
        for(int r=0; r<4; r++){
          int lr = wm*64 + fi*16 + ((lane>>4)<<2) + r;
          int rm = (r0 + lr < cnt) ? idxl[pos0 + lr] : -1;
          if(rm < 0) continue;
          int col = n0 + wn*64 + fj*16 + (lane&15);
          float vv = acc[fi][fj][r] + (kc==0 ? bias[col] : 0.f);
          outp[(size_t)rm*Dm + col] = (short)f2bf(vv * tokp[rm]);
        }
  }
}

// ================= batch-level routing =================
__global__ __launch_bounds__(256) void k_route_batch(const float* __restrict__ xf,
    const float* __restrict__ sw_w, const float* __restrict__ sw_b,
    float* __restrict__ pmax_b, int* __restrict__ route_b){
  int b = blockIdx.x, tid = threadIdx.x;
  __shared__ float xm[Dm];
  for(int d=tid; d<Dm; d+=256){
    float s=0.f;
    const float* xp = xf + ((size_t)b*Sm)*Dm + d;
    for(int ss=0; ss<Sm; ss++) s += xp[(size_t)ss*Dm];
    xm[d] = s*(1.0f/Sm);
  }
  __syncthreads();
  float a0=0,a1=0,a2=0,a3=0;
  for(int d=tid; d<Dm; d+=256){
    float xv = xm[d];
    a0 += xv*sw_w[d*4+0]; a1 += xv*sw_w[d*4+1];
    a2 += xv*sw_w[d*4+2]; a3 += xv*sw_w[d*4+3];
  }
  __shared__ float red[4][256];
  red[0][tid]=a0; red[1][tid]=a1; red[2][tid]=a2; red[3][tid]=a3;
  for(int off=128; off>0; off>>=1){
    __syncthreads();
    if(tid<off){ for(int u=0;u<4;u++) red[u][tid]+=red[u][tid+off]; }
  }
  __syncthreads();
  if(tid==0){
    float l[4]; for(int u=0;u<4;u++) l[u]=red[u][0]+sw_b[u];
    float m=l[0]; int arg=0;
    for(int u=1;u<4;u++) if(l[u]>m){ m=l[u]; arg=u; }
    float s=0; for(int u=0;u<4;u++) s+=expf(l[u]-m);
    pmax_b[b]=1.0f/s;
    route_b[b]=arg;
  }
}

// ====== attention v2: reg-resident scores, wave-local softmax, conflict-free LDS ======
__global__ __launch_bounds__(256) void k_attn_f(const float* __restrict__ qkv,
    const float* __restrict__ mask, const float* __restrict__ pmaxb,
    short* __restrict__ ctx_hi, short* __restrict__ ctx_lo)
{
  int h = blockIdx.x, b = blockIdx.y, z = blockIdx.z;
  int qh = z & 1, kind = z >> 1;
  const float* Q  = qkv + (size_t)(kind*3+0)*NT*Dm;
  const float* Kp = qkv + (size_t)(kind*3+1)*NT*Dm;
  const float* Vp = qkv + (size_t)(kind*3+2)*NT*Dm;
  int tid = threadIdx.x;
  __shared__ float kv[128][68];
  size_t base = ((size_t)b*Sm)*Dm + h*DHm;
  for(int l=tid; l<2048; l+=256){
    int s=l>>4, d4=(l&15)*4;
    *(float4*)&kv[s][d4] = *(const float4*)(Kp + base + (size_t)s*Dm + d4);
  }
  int ql = tid>>2, quarter = tid&3;
  int qi = qh*64 + ql;
  float4 q4[16];
  const float* qp = Q + base + (size_t)qi*Dm;
  #pragma unroll
  for(int j=0;j<16;j++) q4[j] = *(const float4*)(qp + j*4);
  __syncthreads();
  float sc[32];
  #pragma unroll 4
  for(int t=0;t<32;t++){
    int ki = quarter + 4*t;
    float s=0.f;
    #pragma unroll
    for(int j=0;j<16;j++){
      float4 k4 = *(float4*)&kv[ki][j*4];
      s += q4[j].x*k4.x + q4[j].y*k4.y + q4[j].z*k4.z + q4[j].w*k4.w;
    }
    sc[t] = s*0.125f + mask[b*Sm+ki];
  }
  float m = sc[0];
  #pragma unroll
  for(int t=1;t<32;t++) m = fmaxf(m, sc[t]);
  m = fmaxf(m, __shfl_xor(m,1));
  m = fmaxf(m, __shfl_xor(m,2));
  float sum = 0.f;
  #pragma unroll
  for(int t=0;t<32;t++){ sc[t] = expf(sc[t]-m); sum += sc[t]; }
  sum += __shfl_xor(sum,1);
  sum += __shfl_xor(sum,2);
  float inv = 1.0f/sum;
  #pragma unroll
  for(int t=0;t<32;t++) sc[t] *= inv;
  __syncthreads();
  for(int l=tid; l<2048; l+=256){
    int s=l>>4, d4=(l&15)*4;
    *(float4*)&kv[s][d4] = *(const float4*)(Vp + base + (size_t)s*Dm + d4);
  }
  __syncthreads();
  float4 part[16];
  #pragma unroll
  for(int j=0;j<16;j++){ part[j].x=0; part[j].y=0; part[j].z=0; part[j].w=0; }
  #pragma unroll 4
  for(int t=0;t<32;t++){
    int ki = quarter + 4*t;
    float p = sc[t];
    #pragma unroll
    for(int j=0;j<16;j++){
      float4 v4 = *(float4*)&kv[ki][j*4];
      part[j].x += p*v4.x; part[j].y += p*v4.y; part[j].z += p*v4.z; part[j].w += p*v4.w;
    }
  }
  #pragma unroll
  for(int j=0;j<16;j++){
    part[j].x += __shfl_xor(part[j].x,1); part[j].x += __shfl_xor(part[j].x,2);
    part[j].y += __shfl_xor(part[j].y,1); part[j].y += __shfl_xor(part[j].y,2);
    part[j].z += __shfl_xor(part[j].z,1); part[j].z += __shfl_xor(part[j].z,2);
    part[j].w += __shfl_xor(part[j].w,1); part[j].w += __shfl_xor(part[j].w,2);
  }
  float sck = kind ? pmaxb[b] : 1.0f;
  size_t obase = ((size_t)b*Sm + qi)*1536 + kind*Dm + h*DHm;
  #pragma unroll
  for(int jj=0;jj<4;jj++){
    int j = quarter*4 + jj;
    float4 v = part[j];
    v.x *= sck; v.y *= sck; v.z *= sck; v.w *= sck;
    short4 hh, ll;
    unsigned short t0;
    t0=f2bf(v.x); hh.x=(short)t0; ll.x=(short)f2bf(v.x-bf2f(t0));
    t0=f2bf(v.y); hh.y=(short)t0; ll.y=(short)f2bf(v.y-bf2f(t0));
    t0=f2bf(v.z); hh.z=(short)t0; ll.z=(short)f2bf(v.z-bf2f(t0));
    t0=f2bf(v.w); hh.w=(short)t0; ll.w=(short)f2bf(v.w-bf2f(t0));
    *(short4*)(ctx_hi + obase + j*4) = hh;
    *(short4*)(ctx_lo + obase + j*4) = ll;
  }
}

// ================= token-level Switch routing =================
__global__ __launch_bounds__(256) void k_tok_route(const float* __restrict__ att,
    const float* __restrict__ ur_w, const float* __restrict__ ur_b,
    const int* __restrict__ route_b, float* __restrict__ tok_pmax,
    int* __restrict__ tok_e, int* __restrict__ grp_count)
{
  int n = blockIdx.x, tid = threadIdx.x;
  int i = route_b[n>>7];
  const float* w = ur_w + (size_t)i*Dm*4;
  const float* ap = att + (size_t)n*Dm;
  float a0=0,a1=0,a2=0,a3=0;
  for(int d=tid; d<Dm; d+=256){
    float a = ap[d];
    a0 += a*w[d*4+0]; a1 += a*w[d*4+1];
    a2 += a*w[d*4+2]; a3 += a*w[d*4+3];
  }
  __shared__ float red[4][256];
  red[0][tid]=a0; red[1][tid]=a1; red[2][tid]=a2; red[3][tid]=a3;
  for(int off=128; off>0; off>>=1){
    __syncthreads();
    if(tid<off){ for(int u=0;u<4;u++) red[u][tid]+=red[u][tid+off]; }
  }
  __syncthreads();
  if(tid==0){
    float l[4]; for(int u=0;u<4;u++) l[u]=red[u][0]+ur_b[i*4+u];
    float m=l[0]; int arg=0;
    for(int u=1;u<4;u++) if(l[u]>m){ m=l[u]; arg=u; }
    float s=0; for(int u=0;u<4;u++) s+=expf(l[u]-m);
    tok_pmax[n] = 1.0f/s;
    tok_e[n] = arg;
    atomicAdd(&grp_count[i*4+arg], 1);
  }
}

// ================= prefix + tile worklist (BM2-row tiles) =================
__global__ void k_prefix(const int* __restrict__ cnt, int* __restrict__ base,
                         int* __restrict__ cur, int* __restrict__ tlist, int* __restrict__ ntl){
  if(threadIdx.x==0 && blockIdx.x==0){
    int s=0, nt=0;
    for(int g=0; g<16; g++){
      base[g]=s; cur[g]=s;
      int tg = (cnt[g] + BM2 - 1)/BM2;
      for(int t=0; t<tg; t++){ if(nt<32) tlist[nt++] = (g<<8)|t; }
      s += cnt[g];
    }
    ntl[0] = nt;
  }
}

__global__ void k_scatter(const int* __restrict__ route_b, const int* __restrict__ tok_e,
                          int* __restrict__ cur, int* __restrict__ idxl){
  int n = blockIdx.x*256 + threadIdx.x;
  if(n < NT){
    int g = route_b[n>>7]*4 + tok_e[n];
    int pos = atomicAdd(&cur[g], 1);
    idxl[pos] = n;
  }
}

// ======= final residual add + LayerNorm (sums 4+4 bf16 split-K partials) =======
__global__ __launch_bounds__(256) void k_final_ln(const float* __restrict__ att,
    const short* __restrict__ ycf4, const short* __restrict__ yuo4,
    const float* __restrict__ ln_g, const float* __restrict__ ln_b, float* __restrict__ out)
{
  int n = blockIdx.x, tid = threadIdx.x;
  __shared__ float yb[Dm];
  __shared__ float red[256];
  size_t base = (size_t)n*Dm;
  const size_t P = (size_t)NT*Dm;
  float ps = 0.f;
  for(int d=tid; d<Dm; d+=256){
    float v = att[base+d];
    #pragma unroll
    for(int c=0; c<4; c++){
      v += bf2f((unsigned short)ycf4[c*P + base + d]);
      v += bf2f((unsigned short)yuo4[c*P + base + d]);
    }
    yb[d]=v; ps+=v;
  }
  red[tid]=ps;
  for(int off=128; off>0; off>>=1){ __syncthreads(); if(tid<off) red[tid]+=red[tid+off]; }
  __syncthreads();
  float mu = red[0]*(1.0f/Dm);
  __syncthreads();
  float pv = 0.f;
  for(int d=tid; d<Dm; d+=256){ float t = yb[d]-mu; pv += t*t; }
  red[tid]=pv;
  for(int off=128; off>0; off>>=1){ __syncthreads(); if(tid<off) red[tid]+=red[tid+off]; }
  __syncthreads();
  float var = red[0]*(1.0f/Dm);
  float rstd = rsqrtf(var + 1e-12f);
  for(int d=tid; d<Dm; d+=256){
    out[base+d] = (yb[d]-mu)*rstd*ln_g[d] + ln_b[d];
  }
}

extern "C" void kernel_launch(void* const* d_in, const int* in_sizes, int n_in,
                              void* d_out, int out_size, void* d_ws, size_t ws_size,
                              hipStream_t stream)
{
  const float* x     =(const float*)d_in[0];
  const float* mask  =(const float*)d_in[1];
  const float* sw_w  =(const float*)d_in[2];
  const float* sw_b  =(const float*)d_in[3];
  const float* ca_wq =(const float*)d_in[4];
  const float* ca_bq =(const float*)d_in[5];
  const float* ca_wk =(const float*)d_in[6];
  const float* ca_bk =(const float*)d_in[7];
  const float* ca_wv =(const float*)d_in[8];
  const float* ca_bv =(const float*)d_in[9];
  const float* ca_wo =(const float*)d_in[10];
  const float* ca_bo =(const float*)d_in[11];
  const float* ua_wq =(const float*)d_in[12];
  const float* ua_bq =(const float*)d_in[13];
  const float* ua_wk =(const float*)d_in[14];
  const float* ua_bk =(const float*)d_in[15];
  const float* ua_wv =(const float*)d_in[16];
  const float* ua_bv =(const float*)d_in[17];
  const float* ua_wo =(const float*)d_in[18];
  const float* ua_bo =(const float*)d_in[19];
  const float* cf_w1 =(const float*)d_in[20];
  const float* cf_b1 =(const float*)d_in[21];
  const float* cf_w2 =(const float*)d_in[22];
  const float* cf_b2 =(const float*)d_in[23];
  const float* ur_w  =(const float*)d_in[24];
  const float* ur_b  =(const float*)d_in[25];
  const float* uf_w1 =(const float*)d_in[26];
  const float* uf_b1 =(const float*)d_in[27];
  const float* uf_w2 =(const float*)d_in[28];
  const float* uf_b2 =(const float*)d_in[29];
  const float* ln_g  =(const float*)d_in[30];
  const float* ln_b  =(const float*)d_in[31];

  // ---- workspace: region of 8 units (1 unit = NT*Dm f32 = 6.29MB), phase-aliased ----
  // phase A : qkv f32 u0-5 | ctx_hi u6 | ctx_lo u7
  // phase A2: att4 f32 partials u0-3 (qkv dead)
  // phase B : hp (h chunk0/final) u0-1 | hp1 (h chunk1; later ycf4) u2-3 |
  //           hgp (hg chunk0/final) u4-5 | hgp1 (hg chunk1; later yuo4) u6-7
  float* region = (float*)d_ws;
  float* qkv    = region;
  short* ctx_hi = (short*)(region + (size_t)6*NT*Dm);
  short* ctx_lo = (short*)(region + (size_t)7*NT*Dm);
  float* att4   = region;
  short* hp     = (short*)region;                          // u0-1 + u2-3 (2 chunks)
  short* hgp    = (short*)(region + (size_t)4*NT*Dm);      // u4-5 + u6-7 (2 chunks)
  short* ycf4   = (short*)(region + (size_t)2*NT*Dm);      // u2-3 (h chunk1 dead)
  short* yuo4   = (short*)(region + (size_t)6*NT*Dm);      // u6-7 (hg chunk1 dead)
  float* fp     = region + (size_t)8*NT*Dm;
  short* x_hi   = (short*)fp;                 // alive only during mm3_qkv
  short* x_lo   = x_hi + (size_t)NT*Dm;
  float* att    = fp; fp += (size_t)NT*Dm;    // written by k_att_sum (x_hi/lo dead)
  float* tokp   = fp; fp += NT;
  float* pmaxb  = fp; fp += 16;
  short* att_bf = (short*)fp;
  int*   ip     = (int*)(att_bf + (size_t)NT*Dm);
  int* routeb = ip; ip += 16;
  int* toke   = ip; ip += NT;
  int* gcnt   = ip; ip += 16;
  int* gbase  = ip; ip += 16;
  int* gcur   = ip; ip += 16;
  int* idxl   = ip; ip += NT;
  int* tlist  = ip; ip += 64;
  int* ntl    = ip; ip += 1;
  size_t need = (size_t)((char*)ip - (char*)d_ws);
  if(need > ws_size) return;   // bail visibly (output stays 0)

  (void)hipMemsetAsync(gcnt, 0, 16*sizeof(int), stream);

  k_route_batch<<<16, 256, 0, stream>>>(x, sw_w, sw_b, pmaxb, routeb);
  k_split_x<<<(NT*Dm/4 + 255)/256, 256, 0, stream>>>(x, x_hi, x_lo, NT*Dm/4);

  PtrArr6 pa;
  pa.w[0]=ca_wq; pa.w[1]=ca_wk; pa.w[2]=ca_wv; pa.w[3]=ua_wq; pa.w[4]=ua_wk; pa.w[5]=ua_wv;
  pa.b[0]=ca_bq; pa.b[1]=ca_bk; pa.b[2]=ca_bv; pa.b[3]=ua_bq; pa.b[4]=ua_bk; pa.b[5]=ua_bv;
  mm3_qkv<<<dim3(Dm/BN, NT/BM, 6), 256, 0, stream>>>(x_hi, x_lo, pa, routeb, qkv);

  // attention v2 (f32 -> ctx hi/lo bf16): z = qh + 2*kind
  k_attn_f<<<dim3(Hm, Bm, 4), 256, 0, stream>>>(qkv, mask, pmaxb, ctx_hi, ctx_lo);

  // output projection, split-K=4 (z): partials into dead qkv units 0-3
  mm3_outproj<<<dim3(Dm/BN, NT/BM, 4), 256, 0, stream>>>(ctx_hi, ctx_lo, ca_wo, ua_wo,
                                                         ca_bo, ua_bo, routeb, pmaxb, att4);
  k_att_sum<<<(NT*Dm/4 + 255)/256, 256, 0, stream>>>(att4, att, att_bf, NT*Dm/4);

  // token routing + grouping (from f32 att -> flip-safe)
  k_tok_route<<<NT, 256, 0, stream>>>(att, ur_w, ur_b, routeb, tokp, toke, gcnt);
  k_prefix<<<1, 64, 0, stream>>>(gcnt, gbase, gcur, tlist, ntl);
  k_scatter<<<NT/256, 256, 0, stream>>>(routeb, toke, gcur, idxl);

  // F-stage: split-K=2, bf16 pre-activation partials
  mm_fstage<<<dim3(Fm/BN, 16+32, 2), 256, 0, stream>>>(att_bf, cf_w1, cf_b1, uf_w1, uf_b1,
                                                       idxl, gbase, gcnt, tlist, ntl, hp, hgp);
  // combine: h = gelu(c0+c1) in place over chunk 0 (same for hg)
  k_hcombine<<<(NT*Fm/4 + 255)/256, 256, 0, stream>>>(hp + (size_t)NT*Fm, hp, NT*Fm/4);
  k_hcombine<<<(NT*Fm/4 + 255)/256, 256, 0, stream>>>(hgp + (size_t)NT*Fm, hgp, NT*Fm/4);

  // D-stage: panel-major grid (24, 48) — weight-panel L2 locality per XCD
  mm_dstage<<<dim3(24, 16+32), 256, 0, stream>>>(hp, hgp, cf_w2, cf_b2, uf_w2, uf_b2,
                                                 idxl, gbase, gcnt, tlist, ntl, tokp,
                                                 ycf4, yuo4);

  k_final_ln<<<NT, 256, 0, stream>>>(att, ycf4, yuo4, ln_g, ln_b, (float*)d_out);
}

// Round 16
// 546.867 us; speedup vs baseline: 1.0516x; 1.0516x over previous
//
#include <hip/hip_runtime.h>

#define NT 2048
#define Dm 768
#define Fm 3072
#define Bm 16
#define Sm 128
#define Hm 12
#define DHm 64

#define BM 64
#define BM2 128
#define BN 128
#define BK 32

typedef __attribute__((ext_vector_type(8))) short bf16x8;
typedef __attribute__((ext_vector_type(4))) float f32x4;

__device__ __forceinline__ unsigned short f2bf(float f){
  unsigned u = __float_as_uint(f);
  unsigned r = (u + 0x7fffu + ((u>>16)&1u)) >> 16;   // round-nearest-even
  return (unsigned short)r;
}
__device__ __forceinline__ float bf2f(unsigned short h){ return __uint_as_float(((unsigned)h)<<16); }
__device__ __forceinline__ unsigned fsplit2(float x){
  unsigned short h = f2bf(x);
  unsigned short l = f2bf(x - bf2f(h));
  return (unsigned)h | ((unsigned)l << 16);
}
// fast hi/lo split of TWO floats via hardware packed cvt (RNE, bit-identical to f2bf):
__device__ __forceinline__ void bsplit2(float a, float b, unsigned &hi2, unsigned &lo2){
  asm("v_cvt_pk_bf16_f32 %0, %1, %2" : "=v"(hi2) : "v"(a), "v"(b));
  float fa = __uint_as_float(hi2 << 16);
  float fb = __uint_as_float(hi2 & 0xffff0000u);
  asm("v_cvt_pk_bf16_f32 %0, %1, %2" : "=v"(lo2) : "v"(a - fa), "v"(b - fb));
}
__device__ __forceinline__ float gelu_f(float x){
  return 0.5f*x*(1.0f + erff(x*0.70710678118654752f));
}

// ========== barrier-free reg-direct bf16 tile loop, BM2=128, 1-deep prefetch ==========
__device__ __forceinline__ void mm_tile2(
    const short* __restrict__ Abf, int lda,
    const int* __restrict__ gidx, int m0, int mbound,
    const float* __restrict__ W0, int N, int K, int n0,
    f32x4 acc[4][4])
{
  int lane = threadIdx.x & 63, wv = threadIdx.x >> 6;
  int wm = wv & 1, wn = wv >> 1;
  int oct = lane >> 4, l16 = lane & 15;
  const short* aptr[4];
  #pragma unroll
  for(int fi=0; fi<4; fi++){
    int lr = wm*64 + fi*16 + l16;
    int grow = (lr < mbound) ? (gidx ? gidx[m0 + lr] : (m0 + lr)) : -1;
    aptr[fi] = (grow >= 0) ? (Abf + (size_t)grow*lda + oct*8) : nullptr;
  }
  const float* bptr[4];
  #pragma unroll
  for(int fj=0; fj<4; fj++)
    bptr[fj] = W0 + (size_t)(oct*8)*N + (n0 + wn*64 + fj*16 + l16);

  const bf16x8 zz = {0,0,0,0,0,0,0,0};
  bf16x8 av[4]; float bw[4][8];
  #pragma unroll
  for(int fi=0; fi<4; fi++) av[fi] = aptr[fi] ? *(const bf16x8*)(aptr[fi]) : zz;
  #pragma unroll
  for(int fj=0; fj<4; fj++)
    #pragma unroll
    for(int i=0;i<8;i++) bw[fj][i] = bptr[fj][(size_t)i*N];

  for(int k0=0; k0<K; k0+=BK){
    bf16x8 af[4];
    #pragma unroll
    for(int fi=0; fi<4; fi++) af[fi] = av[fi];
    bf16x8 bfr[4];
    #pragma unroll
    for(int fj=0; fj<4; fj++){
      unsigned o0,o1,o2,o3;
      asm("v_cvt_pk_bf16_f32 %0, %1, %2" : "=v"(o0) : "v"(bw[fj][0]), "v"(bw[fj][1]));
      asm("v_cvt_pk_bf16_f32 %0, %1, %2" : "=v"(o1) : "v"(bw[fj][2]), "v"(bw[fj][3]));
      asm("v_cvt_pk_bf16_f32 %0, %1, %2" : "=v"(o2) : "v"(bw[fj][4]), "v"(bw[fj][5]));
      asm("v_cvt_pk_bf16_f32 %0, %1, %2" : "=v"(o3) : "v"(bw[fj][6]), "v"(bw[fj][7]));
      union{ bf16x8 v; unsigned u[4]; } r;
      r.u[0]=o0; r.u[1]=o1; r.u[2]=o2; r.u[3]=o3;
      bfr[fj] = r.v;
    }
    if(k0+BK < K){
      int kn = k0 + BK;
      #pragma unroll
      for(int fi=0; fi<4; fi++) av[fi] = aptr[fi] ? *(const bf16x8*)(aptr[fi] + kn) : zz;
      #pragma unroll
      for(int fj=0; fj<4; fj++)
        #pragma unroll
        for(int i=0;i<8;i++) bw[fj][i] = bptr[fj][(size_t)(kn + i)*N];
    }
    __builtin_amdgcn_s_setprio(1);
    #pragma unroll
    for(int fi=0; fi<4; fi++)
      #pragma unroll
      for(int fj=0; fj<4; fj++)
        acc[fi][fj] = __builtin_amdgcn_mfma_f32_16x16x32_bf16(af[fi], bfr[fj], acc[fi][fj], 0, 0, 0);
    __builtin_amdgcn_s_setprio(0);
  }
}

// ===== barrier-free split-bf16 tile loop: A pre-split hi/lo, W fast-split via cvt_pk =====
__device__ __forceinline__ void mm_tile3b(
    const short* __restrict__ Ahi, const short* __restrict__ Alo, int lda, int m0, int acol,
    const float* __restrict__ W0, int N, int K, int n0,
    f32x4 acc[2][4])
{
  int lane = threadIdx.x & 63, wv = threadIdx.x >> 6;
  int wm = wv & 1, wn = wv >> 1;
  int oct = lane >> 4, l16 = lane & 15;
  size_t aoffs[2];
  #pragma unroll
  for(int fi=0; fi<2; fi++){
    int lr = wm*32 + fi*16 + l16;
    aoffs[fi] = (size_t)(m0 + lr)*lda + acol + oct*8;
  }
  const float* bptr[4];
  #pragma unroll
  for(int fj=0; fj<4; fj++)
    bptr[fj] = W0 + (size_t)(oct*8)*N + (n0 + wn*64 + fj*16 + l16);

  bf16x8 avH[2], avL[2]; float bw[4][8];
  #pragma unroll
  for(int fi=0; fi<2; fi++){
    avH[fi] = *(const bf16x8*)(Ahi + aoffs[fi]);
    avL[fi] = *(const bf16x8*)(Alo + aoffs[fi]);
  }
  #pragma unroll
  for(int fj=0; fj<4; fj++)
    #pragma unroll
    for(int i=0;i<8;i++) bw[fj][i] = bptr[fj][(size_t)i*N];

  for(int k0=0; k0<K; k0+=BK){
    bf16x8 ah[2], al[2];
    #pragma unroll
    for(int fi=0; fi<2; fi++){ ah[fi]=avH[fi]; al[fi]=avL[fi]; }
    bf16x8 bh[4], bl[4];
    #pragma unroll
    for(int fj=0; fj<4; fj++){
      unsigned h0,l0,h1,l1,h2,l2,h3,l3;
      bsplit2(bw[fj][0], bw[fj][1], h0, l0);
      bsplit2(bw[fj][2], bw[fj][3], h1, l1);
      bsplit2(bw[fj][4], bw[fj][5], h2, l2);
      bsplit2(bw[fj][6], bw[fj][7], h3, l3);
      union{ bf16x8 v; unsigned u[4]; } rh, rl;
      rh.u[0]=h0; rh.u[1]=h1; rh.u[2]=h2; rh.u[3]=h3;
      rl.u[0]=l0; rl.u[1]=l1; rl.u[2]=l2; rl.u[3]=l3;
      bh[fj] = rh.v; bl[fj] = rl.v;
    }
    if(k0+BK < K){
      int kn = k0 + BK;
      #pragma unroll
      for(int fi=0; fi<2; fi++){
        avH[fi] = *(const bf16x8*)(Ahi + aoffs[fi] + kn);
        avL[fi] = *(const bf16x8*)(Alo + aoffs[fi] + kn);
      }
      #pragma unroll
      for(int fj=0; fj<4; fj++)
        #pragma unroll
        for(int i=0;i<8;i++) bw[fj][i] = bptr[fj][(size_t)(kn + i)*N];
    }
    __builtin_amdgcn_s_setprio(1);
    #pragma unroll
    for(int fi=0; fi<2; fi++)
      #pragma unroll
      for(int fj=0; fj<4; fj++){
        acc[fi][fj] = __builtin_amdgcn_mfma_f32_16x16x32_bf16(ah[fi], bh[fj], acc[fi][fj], 0, 0, 0);
        acc[fi][fj] = __builtin_amdgcn_mfma_f32_16x16x32_bf16(ah[fi], bl[fj], acc[fi][fj], 0, 0, 0);
        acc[fi][fj] = __builtin_amdgcn_mfma_f32_16x16x32_bf16(al[fi], bh[fj], acc[fi][fj], 0, 0, 0);
      }
    __builtin_amdgcn_s_setprio(0);
  }
}

// ================= x -> hi/lo bf16 pre-split =================
__global__ __launch_bounds__(256) void k_split_x(const float* __restrict__ in,
    short* __restrict__ hi, short* __restrict__ lo, int n4){
  int i = blockIdx.x*256 + threadIdx.x;
  if(i < n4){
    float4 v = ((const float4*)in)[i];
    unsigned h01,l01,h23,l23;
    bsplit2(v.x, v.y, h01, l01);
    bsplit2(v.z, v.w, h23, l23);
    short4 h, l;
    h.x=(short)(h01&0xffff); h.y=(short)(h01>>16); h.z=(short)(h23&0xffff); h.w=(short)(h23>>16);
    l.x=(short)(l01&0xffff); l.y=(short)(l01>>16); l.z=(short)(l23&0xffff); l.w=(short)(l23>>16);
    ((short4*)hi)[i] = h;
    ((short4*)lo)[i] = l;
  }
}

// ================= fused QKV (common + unique), split precision, f32 out =================
struct PtrArr6 { const float* w[6]; const float* b[6]; };

__global__ __launch_bounds__(256) void mm3_qkv(const short* __restrict__ x_hi,
    const short* __restrict__ x_lo, PtrArr6 pa,
    const int* __restrict__ routeb, float* __restrict__ qkvout)
{
  int n0 = blockIdx.x*BN, m0 = blockIdx.y*BM, z = blockIdx.z;
  int bidx = m0 >> 7;
  const float* W = pa.w[z]; const float* bias = pa.b[z];
  if(z >= 3){ int e = routeb[bidx]; W += (size_t)e*Dm*Dm; bias += (size_t)e*Dm; }
  f32x4 acc[2][4] = {};
  mm_tile3b(x_hi, x_lo, Dm, m0, 0, W, Dm, Dm, n0, acc);
  float* outp = qkvout + (size_t)z*NT*Dm;
  int lane = threadIdx.x&63, wv = threadIdx.x>>6, wm = wv&1, wn = wv>>1;
  #pragma unroll
  for(int fi=0; fi<2; fi++)
    #pragma unroll
    for(int fj=0; fj<4; fj++)
      #pragma unroll
      for(int r=0; r<4; r++){
        int row = m0 + wm*32 + fi*16 + ((lane>>4)<<2) + r;
        int col = n0 + wn*64 + fj*16 + (lane&15);
        outp[(size_t)row*Dm + col] = acc[fi][fj][r] + bias[col];
      }
}

// ====== output projection, split-K=4 via z: kc/2 selects {common,unique}, kc&1 selects k-half ======
__global__ __launch_bounds__(256) void mm3_outproj(const short* __restrict__ ctx_hi,
    const short* __restrict__ ctx_lo,
    const float* __restrict__ ca_wo, const float* __restrict__ ua_wo,
    const float* __restrict__ ca_bo, const float* __restrict__ ua_bo,
    const int* __restrict__ routeb, const float* __restrict__ pmaxb,
    float* __restrict__ att4)
{
  const int KC = Dm/2;   // 384
  int n0 = blockIdx.x*BN, m0 = blockIdx.y*BM, kc = blockIdx.z;
  int bidx = m0 >> 7;
  int e = routeb[bidx];
  int uq = kc >> 1, kh = kc & 1;
  const float* Wb = uq ? (ua_wo + (size_t)e*Dm*Dm) : ca_wo;
  const float* W  = Wb + (size_t)kh*KC*Dm;
  int acol = uq*Dm + kh*KC;
  f32x4 acc[2][4] = {};
  mm_tile3b(ctx_hi, ctx_lo, 1536, m0, acol, W, Dm, KC, n0, acc);
  float* outp = att4 + (size_t)kc*NT*Dm;
  int lane = threadIdx.x&63, wv = threadIdx.x>>6, wm = wv&1, wn = wv>>1;
  #pragma unroll
  for(int fi=0; fi<2; fi++)
    #pragma unroll
    for(int fj=0; fj<4; fj++)
      #pragma unroll
      for(int r=0; r<4; r++){
        int row = m0 + wm*32 + fi*16 + ((lane>>4)<<2) + r;
        int col = n0 + wn*64 + fj*16 + (lane&15);
        float bv = 0.f;
        if(kh == 0) bv = uq ? pmaxb[bidx]*ua_bo[(size_t)e*Dm + col] : ca_bo[col];
        outp[(size_t)row*Dm + col] = acc[fi][fj][r] + bv;
      }
}

// ================= att = sum of 4 partials; also emit bf16 =================
__global__ __launch_bounds__(256) void k_att_sum(const float* __restrict__ att4,
    float* __restrict__ att, short* __restrict__ attbf, int n4){
  int i = blockIdx.x*256 + threadIdx.x;
  if(i < n4){
    const size_t P4 = (size_t)NT*Dm/4;
    float4 a = ((const float4*)att4)[i];
    float4 b = ((const float4*)att4)[P4 + i];
    float4 c = ((const float4*)att4)[2*P4 + i];
    float4 d = ((const float4*)att4)[3*P4 + i];
    float4 v;
    v.x=a.x+b.x+c.x+d.x; v.y=a.y+b.y+c.y+d.y;
    v.z=a.z+b.z+c.z+d.z; v.w=a.w+b.w+c.w+d.w;
    ((float4*)att)[i] = v;
    short4 o;
    o.x=(short)f2bf(v.x); o.y=(short)f2bf(v.y); o.z=(short)f2bf(v.z); o.w=(short)f2bf(v.w);
    ((short4*)attbf)[i] = o;
  }
}

// ================= F-stage: common FFN1 (y<16) + grouped Switch-FFN1 (tile list) =================
__global__ __launch_bounds__(256) void mm_fstage(const short* __restrict__ attbf,
    const float* __restrict__ cf_w1, const float* __restrict__ cf_b1,
    const float* __restrict__ uf_w1, const float* __restrict__ uf_b1,
    const int* __restrict__ idxl, const int* __restrict__ gbase, const int* __restrict__ gcnt,
    const int* __restrict__ tlist, const int* __restrict__ ntl,
    short* __restrict__ h, short* __restrict__ hg)
{
  int n0 = blockIdx.x*BN, y = blockIdx.y;
  int lane = threadIdx.x&63, wv = threadIdx.x>>6, wm = wv&1, wn = wv>>1;
  f32x4 acc[4][4] = {};
  if(y < 16){
    int m0 = y*BM2;
    mm_tile2(attbf, Dm, nullptr, m0, BM2, cf_w1, Fm, Dm, n0, acc);
    #pragma unroll
    for(int fi=0; fi<4; fi++)
      #pragma unroll
      for(int fj=0; fj<4; fj++)
        #pragma unroll
        for(int r=0; r<4; r++){
          int row = m0 + wm*64 + fi*16 + ((lane>>4)<<2) + r;
          int col = n0 + wn*64 + fj*16 + (lane&15);
          h[(size_t)row*Fm + col] = (short)f2bf(gelu_f(acc[fi][fj][r] + cf_b1[col]));
        }
  } else {
    int i = y - 16;
    if(i >= ntl[0]) return;
    int v = tlist[i], g = v>>8, t = v&255;
    int cnt = gcnt[g], r0 = t*BM2, pos0 = gbase[g] + r0;
    mm_tile2(attbf, Dm, idxl, pos0, cnt - r0, uf_w1 + (size_t)g*Dm*Fm, Fm, Dm, n0, acc);
    const float* bias = uf_b1 + (size_t)g*Fm;
    #pragma unroll
    for(int fi=0; fi<4; fi++)
      #pragma unroll
      for(int fj=0; fj<4; fj++)
        #pragma unroll
        for(int r=0; r<4; r++){
          int lr = wm*64 + fi*16 + ((lane>>4)<<2) + r;
          if(r0 + lr >= cnt) continue;
          int col = n0 + wn*64 + fj*16 + (lane&15);
          hg[(size_t)(pos0+lr)*Fm + col] = (short)f2bf(gelu_f(acc[fi][fj][r] + bias[col]));
        }
  }
}

// ===== D-stage: panel-major grid (x = bx%6, kc = bx/6), same-panel blocks co-XCD =====
__global__ __launch_bounds__(256) void mm_dstage(const short* __restrict__ h,
    const short* __restrict__ hg,
    const float* __restrict__ cf_w2, const float* __restrict__ cf_b2,
    const float* __restrict__ uf_w2, const float* __restrict__ uf_b2,
    const int* __restrict__ idxl, const int* __restrict__ gbase, const int* __restrict__ gcnt,
    const int* __restrict__ tlist, const int* __restrict__ ntl,
    const float* __restrict__ tokp, short* __restrict__ ycf4, short* __restrict__ yuo4)
{
  const int KC = Fm/4;   // 768
  int bx = blockIdx.x;
  int n0 = (bx % 6)*BN, kc = bx / 6;
  int y = blockIdx.y;
  int lane = threadIdx.x&63, wv = threadIdx.x>>6, wm = wv&1, wn = wv>>1;
  f32x4 acc[4][4] = {};
  if(y < 16){
    int m0 = y*BM2;
    mm_tile2(h + kc*KC, Fm, nullptr, m0, BM2, cf_w2 + (size_t)kc*KC*Dm, Dm, KC, n0, acc);
    short* outp = ycf4 + (size_t)kc*NT*Dm;
    #pragma unroll
    for(int fi=0; fi<4; fi++)
      #pragma unroll
      for(int fj=0; fj<4; fj++)
        #pragma unroll
        for(int r=0; r<4; r++){
          int row = m0 + wm*64 + fi*16 + ((lane>>4)<<2) + r;
          int col = n0 + wn*64 + fj*16 + (lane&15);
          outp[(size_t)row*Dm + col] = (short)f2bf(acc[fi][fj][r] + (kc==0 ? cf_b2[col] : 0.f));
        }
  } else {
    int i = y - 16;
    if(i >= ntl[0]) return;
    int v = tlist[i], g = v>>8, t = v&255;
    int cnt = gcnt[g], r0 = t*BM2, pos0 = gbase[g] + r0;
    mm_tile2(hg + kc*KC, Fm, nullptr, pos0, cnt - r0,
             uf_w2 + (size_t)g*Fm*Dm + (size_t)kc*KC*Dm, Dm, KC, n0, acc);
    const float* bias = uf_b2 + (size_t)g*Dm;
    short* outp = yuo4 + (size_t)kc*NT*Dm;
    #pragma unroll
    for(int fi=0; fi<4; fi++)
      #pragma unroll
      for(int fj=0; fj<4; fj++)
        #pragma unroll
        for(int r=0; r<4; r++){
          int lr = wm*64 + fi*16 + ((lane>>4)<<2) + r;
          int rm = (r0 + lr < cnt) ? idxl[pos0 + lr] : -1;
          if(rm < 0) continue;
          int col = n0 + wn*64 + fj*16 + (lane&15);
          float vv = acc[fi][fj][r] + (kc==0 ? bias[col] : 0.f);
          outp[(size_t)rm*Dm + col] = (short)f2bf(vv * tokp[rm]);
        }
  }
}

// ================= batch-level routing =================
__global__ __launch_bounds__(256) void k_route_batch(const float* __restrict__ xf,
    const float* __restrict__ sw_w, const float* __restrict__ sw_b,
    float* __restrict__ pmax_b, int* __restrict__ route_b){
  int b = blockIdx.x, tid = threadIdx.x;
  __shared__ float xm[Dm];
  for(int d=tid; d<Dm; d+=256){
    float s=0.f;
    const float* xp = xf + ((size_t)b*Sm)*Dm + d;
    for(int ss=0; ss<Sm; ss++) s += xp[(size_t)ss*Dm];
    xm[d] = s*(1.0f/Sm);
  }
  __syncthreads();
  float a0=0,a1=0,a2=0,a3=0;
  for(int d=tid; d<Dm; d+=256){
    float xv = xm[d];
    a0 += xv*sw_w[d*4+0]; a1 += xv*sw_w[d*4+1];
    a2 += xv*sw_w[d*4+2]; a3 += xv*sw_w[d*4+3];
  }
  __shared__ float red[4][256];
  red[0][tid]=a0; red[1][tid]=a1; red[2][tid]=a2; red[3][tid]=a3;
  for(int off=128; off>0; off>>=1){
    __syncthreads();
    if(tid<off){ for(int u=0;u<4;u++) red[u][tid]+=red[u][tid+off]; }
  }
  __syncthreads();
  if(tid==0){
    float l[4]; for(int u=0;u<4;u++) l[u]=red[u][0]+sw_b[u];
    float m=l[0]; int arg=0;
    for(int u=1;u<4;u++) if(l[u]>m){ m=l[u]; arg=u; }
    float s=0; for(int u=0;u<4;u++) s+=expf(l[u]-m);
    pmax_b[b]=1.0f/s;
    route_b[b]=arg;
  }
}

// ====== attention v2: reg-resident scores, wave-local softmax, conflict-free LDS ======
__global__ __launch_bounds__(256) void k_attn_f(const float* __restrict__ qkv,
    const float* __restrict__ mask, const float* __restrict__ pmaxb,
    short* __restrict__ ctx_hi, short* __restrict__ ctx_lo)
{
  int h = blockIdx.x, b = blockIdx.y, z = blockIdx.z;
  int qh = z & 1, kind = z >> 1;
  const float* Q  = qkv + (size_t)(kind*3+0)*NT*Dm;
  const float* Kp = qkv + (size_t)(kind*3+1)*NT*Dm;
  const float* Vp = qkv + (size_t)(kind*3+2)*NT*Dm;
  int tid = threadIdx.x;
  __shared__ float kv[128][68];
  size_t base = ((size_t)b*Sm)*Dm + h*DHm;
  for(int l=tid; l<2048; l+=256){
    int s=l>>4, d4=(l&15)*4;
    *(float4*)&kv[s][d4] = *(const float4*)(Kp + base + (size_t)s*Dm + d4);
  }
  int ql = tid>>2, quarter = tid&3;
  int qi = qh*64 + ql;
  float4 q4[16];
  const float* qp = Q + base + (size_t)qi*Dm;
  #pragma unroll
  for(int j=0;j<16;j++) q4[j] = *(const float4*)(qp + j*4);
  __syncthreads();
  float sc[32];
  #pragma unroll 4
  for(int t=0;t<32;t++){
    int ki = quarter + 4*t;
    float s=0.f;
    #pragma unroll
    for(int j=0;j<16;j++){
      float4 k4 = *(float4*)&kv[ki][j*4];
      s += q4[j].x*k4.x + q4[j].y*k4.y + q4[j].z*k4.z + q4[j].w*k4.w;
    }
    sc[t] = s*0.125f + mask[b*Sm+ki];
  }
  float m = sc[0];
  #pragma unroll
  for(int t=1;t<32;t++) m = fmaxf(m, sc[t]);
  m = fmaxf(m, __shfl_xor(m,1));
  m = fmaxf(m, __shfl_xor(m,2));
  float sum = 0.f;
  #pragma unroll
  for(int t=0;t<32;t++){ sc[t] = expf(sc[t]-m); sum += sc[t]; }
  sum += __shfl_xor(sum,1);
  sum += __shfl_xor(sum,2);
  float inv = 1.0f/sum;
  #pragma unroll
  for(int t=0;t<32;t++) sc[t] *= inv;
  __syncthreads();
  for(int l=tid; l<2048; l+=256){
    int s=l>>4, d4=(l&15)*4;
    *(float4*)&kv[s][d4] = *(const float4*)(Vp + base + (size_t)s*Dm + d4);
  }
  __syncthreads();
  float4 part[16];
  #pragma unroll
  for(int j=0;j<16;j++){ part[j].x=0; part[j].y=0; part[j].z=0; part[j].w=0; }
  #pragma unroll 4
  for(int t=0;t<32;t++){
    int ki = quarter + 4*t;
    float p = sc[t];
    #pragma unroll
    for(int j=0;j<16;j++){
      float4 v4 = *(float4*)&kv[ki][j*4];
      part[j].x += p*v4.x; part[j].y += p*v4.y; part[j].z += p*v4.z; part[j].w += p*v4.w;
    }
  }
  #pragma unroll
  for(int j=0;j<16;j++){
    part[j].x += __shfl_xor(part[j].x,1); part[j].x += __shfl_xor(part[j].x,2);
    part[j].y += __shfl_xor(part[j].y,1); part[j].y += __shfl_xor(part[j].y,2);
    part[j].z += __shfl_xor(part[j].z,1); part[j].z += __shfl_xor(part[j].z,2);
    part[j].w += __shfl_xor(part[j].w,1); part[j].w += __shfl_xor(part[j].w,2);
  }
  float sck = kind ? pmaxb[b] : 1.0f;
  size_t obase = ((size_t)b*Sm + qi)*1536 + kind*Dm + h*DHm;
  #pragma unroll
  for(int jj=0;jj<4;jj++){
    int j = quarter*4 + jj;
    float4 v = part[j];
    v.x *= sck; v.y *= sck; v.z *= sck; v.w *= sck;
    short4 hh, ll;
    unsigned short t0;
    t0=f2bf(v.x); hh.x=(short)t0; ll.x=(short)f2bf(v.x-bf2f(t0));
    t0=f2bf(v.y); hh.y=(short)t0; ll.y=(short)f2bf(v.y-bf2f(t0));
    t0=f2bf(v.z); hh.z=(short)t0; ll.z=(short)f2bf(v.z-bf2f(t0));
    t0=f2bf(v.w); hh.w=(short)t0; ll.w=(short)f2bf(v.w-bf2f(t0));
    *(short4*)(ctx_hi + obase + j*4) = hh;
    *(short4*)(ctx_lo + obase + j*4) = ll;
  }
}

// ================= token-level Switch routing =================
__global__ __launch_bounds__(256) void k_tok_route(const float* __restrict__ att,
    const float* __restrict__ ur_w, const float* __restrict__ ur_b,
    const int* __restrict__ route_b, float* __restrict__ tok_pmax,
    int* __restrict__ tok_e, int* __restrict__ grp_count)
{
  int n = blockIdx.x, tid = threadIdx.x;
  int i = route_b[n>>7];
  const float* w = ur_w + (size_t)i*Dm*4;
  const float* ap = att + (size_t)n*Dm;
  float a0=0,a1=0,a2=0,a3=0;
  for(int d=tid; d<Dm; d+=256){
    float a = ap[d];
    a0 += a*w[d*4+0]; a1 += a*w[d*4+1];
    a2 += a*w[d*4+2]; a3 += a*w[d*4+3];
  }
  __shared__ float red[4][256];
  red[0][tid]=a0; red[1][tid]=a1; red[2][tid]=a2; red[3][tid]=a3;
  for(int off=128; off>0; off>>=1){
    __syncthreads();
    if(tid<off){ for(int u=0;u<4;u++) red[u][tid]+=red[u][tid+off]; }
  }
  __syncthreads();
  if(tid==0){
    float l[4]; for(int u=0;u<4;u++) l[u]=red[u][0]+ur_b[i*4+u];
    float m=l[0]; int arg=0;
    for(int u=1;u<4;u++) if(l[u]>m){ m=l[u]; arg=u; }
    float s=0; for(int u=0;u<4;u++) s+=expf(l[u]-m);
    tok_pmax[n] = 1.0f/s;
    tok_e[n] = arg;
    atomicAdd(&grp_count[i*4+arg], 1);
  }
}

// ================= prefix + tile worklist (BM2-row tiles) =================
__global__ void k_prefix(const int* __restrict__ cnt, int* __restrict__ base,
                         int* __restrict__ cur, int* __restrict__ tlist, int* __restrict__ ntl){
  if(threadIdx.x==0 && blockIdx.x==0){
    int s=0, nt=0;
    for(int g=0; g<16; g++){
      base[g]=s; cur[g]=s;
      int tg = (cnt[g] + BM2 - 1)/BM2;
      for(int t=0; t<tg; t++){ if(nt<32) tlist[nt++] = (g<<8)|t; }
      s += cnt[g];
    }
    ntl[0] = nt;
  }
}

__global__ void k_scatter(const int* __restrict__ route_b, const int* __restrict__ tok_e,
                          int* __restrict__ cur, int* __restrict__ idxl){
  int n = blockIdx.x*256 + threadIdx.x;
  if(n < NT){
    int g = route_b[n>>7]*4 + tok_e[n];
    int pos = atomicAdd(&cur[g], 1);
    idxl[pos] = n;
  }
}

// ======= final residual add + LayerNorm (sums 4+4 bf16 split-K partials) =======
__global__ __launch_bounds__(256) void k_final_ln(const float* __restrict__ att,
    const short* __restrict__ ycf4, const short* __restrict__ yuo4,
    const float* __restrict__ ln_g, const float* __restrict__ ln_b, float* __restrict__ out)
{
  int n = blockIdx.x, tid = threadIdx.x;
  __shared__ float yb[Dm];
  __shared__ float red[256];
  size_t base = (size_t)n*Dm;
  const size_t P = (size_t)NT*Dm;
  float ps = 0.f;
  for(int d=tid; d<Dm; d+=256){
    float v = att[base+d];
    #pragma unroll
    for(int c=0; c<4; c++){
      v += bf2f((unsigned short)ycf4[c*P + base + d]);
      v += bf2f((unsigned short)yuo4[c*P + base + d]);
    }
    yb[d]=v; ps+=v;
  }
  red[tid]=ps;
  for(int off=128; off>0; off>>=1){ __syncthreads(); if(tid<off) red[tid]+=red[tid+off]; }
  __syncthreads();
  float mu = red[0]*(1.0f/Dm);
  __syncthreads();
  float pv = 0.f;
  for(int d=tid; d<Dm; d+=256){ float t = yb[d]-mu; pv += t*t; }
  red[tid]=pv;
  for(int off=128; off>0; off>>=1){ __syncthreads(); if(tid<off) red[tid]+=red[tid+off]; }
  __syncthreads();
  float var = red[0]*(1.0f/Dm);
  float rstd = rsqrtf(var + 1e-12f);
  for(int d=tid; d<Dm; d+=256){
    out[base+d] = (yb[d]-mu)*rstd*ln_g[d] + ln_b[d];
  }
}

extern "C" void kernel_launch(void* const* d_in, const int* in_sizes, int n_in,
                              void* d_out, int out_size, void* d_ws, size_t ws_size,
                              hipStream_t stream)
{
  const float* x     =(const float*)d_in[0];
  const float* mask  =(const float*)d_in[1];
  const float* sw_w  =(const float*)d_in[2];
  const float* sw_b  =(const float*)d_in[3];
  const float* ca_wq =(const float*)d_in[4];
  const float* ca_bq =(const float*)d_in[5];
  const float* ca_wk =(const float*)d_in[6];
  const float* ca_bk =(const float*)d_in[7];
  const float* ca_wv =(const float*)d_in[8];
  const float* ca_bv =(const float*)d_in[9];
  const float* ca_wo =(const float*)d_in[10];
  const float* ca_bo =(const float*)d_in[11];
  const float* ua_wq =(const float*)d_in[12];
  const float* ua_bq =(const float*)d_in[13];
  const float* ua_wk =(const float*)d_in[14];
  const float* ua_bk =(const float*)d_in[15];
  const float* ua_wv =(const float*)d_in[16];
  const float* ua_bv =(const float*)d_in[17];
  const float* ua_wo =(const float*)d_in[18];
  const float* ua_bo =(const float*)d_in[19];
  const float* cf_w1 =(const float*)d_in[20];
  const float* cf_b1 =(const float*)d_in[21];
  const float* cf_w2 =(const float*)d_in[22];
  const float* cf_b2 =(const float*)d_in[23];
  const float* ur_w  =(const float*)d_in[24];
  const float* ur_b  =(const float*)d_in[25];
  const float* uf_w1 =(const float*)d_in[26];
  const float* uf_b1 =(const float*)d_in[27];
  const float* uf_w2 =(const float*)d_in[28];
  const float* uf_b2 =(const float*)d_in[29];
  const float* ln_g  =(const float*)d_in[30];
  const float* ln_b  =(const float*)d_in[31];

  // ---- workspace: region of 8 units (1 unit = NT*Dm f32 = 6.29MB), phase-aliased ----
  float* region = (float*)d_ws;
  float* qkv    = region;
  short* ctx_hi = (short*)(region + (size_t)6*NT*Dm);
  short* ctx_lo = (short*)(region + (size_t)7*NT*Dm);
  float* att4   = region;
  short* h_bf   = (short*)region;
  short* hg_bf  = (short*)region + (size_t)NT*Fm;
  short* ycf4   = (short*)(region + (size_t)4*NT*Dm);
  short* yuo4   = (short*)(region + (size_t)6*NT*Dm);
  float* fp     = region + (size_t)8*NT*Dm;
  short* x_hi   = (short*)fp;                 // alive only during mm3_qkv
  short* x_lo   = x_hi + (size_t)NT*Dm;
  float* att    = fp; fp += (size_t)NT*Dm;    // written by k_att_sum (x_hi/lo dead)
  float* tokp   = fp; fp += NT;
  float* pmaxb  = fp; fp += 16;
  short* att_bf = (short*)fp;
  int*   ip     = (int*)(att_bf + (size_t)NT*Dm);
  int* routeb = ip; ip += 16;
  int* toke   = ip; ip += NT;
  int* gcnt   = ip; ip += 16;
  int* gbase  = ip; ip += 16;
  int* gcur   = ip; ip += 16;
  int* idxl   = ip; ip += NT;
  int* tlist  = ip; ip += 64;
  int* ntl    = ip; ip += 1;
  size_t need = (size_t)((char*)ip - (char*)d_ws);
  if(need > ws_size) return;   // bail visibly (output stays 0)

  (void)hipMemsetAsync(gcnt, 0, 16*sizeof(int), stream);

  k_route_batch<<<16, 256, 0, stream>>>(x, sw_w, sw_b, pmaxb, routeb);
  k_split_x<<<(NT*Dm/4 + 255)/256, 256, 0, stream>>>(x, x_hi, x_lo, NT*Dm/4);

  PtrArr6 pa;
  pa.w[0]=ca_wq; pa.w[1]=ca_wk; pa.w[2]=ca_wv; pa.w[3]=ua_wq; pa.w[4]=ua_wk; pa.w[5]=ua_wv;
  pa.b[0]=ca_bq; pa.b[1]=ca_bk; pa.b[2]=ca_bv; pa.b[3]=ua_bq; pa.b[4]=ua_bk; pa.b[5]=ua_bv;
  mm3_qkv<<<dim3(Dm/BN, NT/BM, 6), 256, 0, stream>>>(x_hi, x_lo, pa, routeb, qkv);

  // attention v2 (f32 -> ctx hi/lo bf16): z = qh + 2*kind
  k_attn_f<<<dim3(Hm, Bm, 4), 256, 0, stream>>>(qkv, mask, pmaxb, ctx_hi, ctx_lo);

  // output projection, split-K=4 (z): partials into dead qkv units 0-3
  mm3_outproj<<<dim3(Dm/BN, NT/BM, 4), 256, 0, stream>>>(ctx_hi, ctx_lo, ca_wo, ua_wo,
                                                         ca_bo, ua_bo, routeb, pmaxb, att4);
  k_att_sum<<<(NT*Dm/4 + 255)/256, 256, 0, stream>>>(att4, att, att_bf, NT*Dm/4);

  // token routing + grouping (from f32 att -> flip-safe)
  k_tok_route<<<NT, 256, 0, stream>>>(att, ur_w, ur_b, routeb, tokp, toke, gcnt);
  k_prefix<<<1, 64, 0, stream>>>(gcnt, gbase, gcur, tlist, ntl);
  k_scatter<<<NT/256, 256, 0, stream>>>(routeb, toke, gcur, idxl);

  // F-stage: common FFN1 (16 tiles of 128) + grouped Switch-FFN1 (<=32 tiles)
  mm_fstage<<<dim3(Fm/BN, 16+32), 256, 0, stream>>>(att_bf, cf_w1, cf_b1, uf_w1, uf_b1,
                                                    idxl, gbase, gcnt, tlist, ntl, h_bf, hg_bf);

  // D-stage: panel-major grid (24, 48) — weight-panel L2 locality per XCD
  mm_dstage<<<dim3(24, 16+32), 256, 0, stream>>>(h_bf, hg_bf, cf_w2, cf_b2, uf_w2, uf_b2,
                                                 idxl, gbase, gcnt, tlist, ntl, tokp,
                                                 ycf4, yuo4);

  k_final_ln<<<NT, 256, 0, stream>>>(att, ycf4, yuo4, ln_g, ln_b, (float*)d_out);
}